// Round 3
// baseline (130.227 us; speedup 1.0000x reference)
//
#include <hip/hip_runtime.h>

typedef _Float16 half8 __attribute__((ext_vector_type(8)));
typedef float f32x4 __attribute__((ext_vector_type(4)));

#define MFMA16(a, b, c) __builtin_amdgcn_mfma_f32_16x16x32_f16((a), (b), (c), 0, 0, 0)

static __device__ __forceinline__ unsigned short hfbits(float f) {
  return __builtin_bit_cast(unsigned short, (_Float16)f);
}

// async global->LDS, 16B per lane; LDS dest = uniform base + lane*16
static __device__ __forceinline__ void gl16(const ushort* g, ushort* l) {
  __builtin_amdgcn_global_load_lds(
      (const __attribute__((address_space(1))) unsigned int*)g,
      (__attribute__((address_space(3))) unsigned int*)l, 16, 0, 0);
}

// ---------------------------------------------------------------------------
// Kernel 1: W [1024][3072] f32 -> Wt [3072][1024] fp16 (transposed + cast).
// Block (0,0) additionally converts mask[2][2048] i32 -> biasf f32 {0,-1e9}
// (consumed by k_attn as the QK MFMA accumulator init = free masking).
// ---------------------------------------------------------------------------
__global__ __launch_bounds__(256) void k_wt(const float* __restrict__ W,
                                            ushort* __restrict__ wt,
                                            const int* __restrict__ mask,
                                            float* __restrict__ biasf) {
  __shared__ ushort tile[64][72];
  const int t = threadIdx.x;
  const int n0 = blockIdx.x * 64, k0 = blockIdx.y * 64;
  if (blockIdx.x == 0 && blockIdx.y == 0) {
#pragma unroll
    for (int i = 0; i < 16; ++i) {
      int p = t + i * 256;
      biasf[p] = mask[p] ? 0.f : -1e9f;
    }
  }
#pragma unroll
  for (int i = 0; i < 4; ++i) {
    int p = t + i * 256;
    int r = p >> 4, c = (p & 15) << 2;
    float4 v = *reinterpret_cast<const float4*>(&W[(size_t)(k0 + r) * 3072 + n0 + c]);
    ushort4 u;
    u.x = hfbits(v.x); u.y = hfbits(v.y); u.z = hfbits(v.z); u.w = hfbits(v.w);
    *reinterpret_cast<ushort4*>(&tile[r][c]) = u;
  }
  __syncthreads();
#pragma unroll
  for (int i = 0; i < 4; ++i) {
    int p = t + i * 256;
    int rn = p >> 4, ck = (p & 15) << 2;
    ushort4 u;
    u.x = tile[ck + 0][rn]; u.y = tile[ck + 1][rn];
    u.z = tile[ck + 2][rn]; u.w = tile[ck + 3][rn];
    *reinterpret_cast<ushort4*>(&wt[(size_t)(n0 + rn) * 1024 + k0 + ck]) = u;
  }
}

// ---------------------------------------------------------------------------
// Kernel 2: qkv = x @ W.  Q outputs pre-scaled by log2(e) so k_attn can use
// exp2 directly (scale applied in f32 before the single f32->f16 round).
// ---------------------------------------------------------------------------
__global__ __launch_bounds__(256) void k_gemm(const float* __restrict__ x,
                                              const ushort* __restrict__ wt,
                                              ushort* __restrict__ qw,
                                              ushort* __restrict__ kw,
                                              ushort* __restrict__ vw) {
  __shared__ ushort sA[128][72];
  __shared__ ushort sB[128][72];
  const int t = threadIdx.x;
  const int lane = t & 63, w = t >> 6;
  const int g = lane >> 4, lr = lane & 15;
  const int wr = w >> 1, wc = w & 1;
  const int bn = blockIdx.x, bm = blockIdx.y;

  f32x4 acc[4][4] = {};

  for (int kt = 0; kt < 1024; kt += 64) {
#pragma unroll
    for (int i = 0; i < 8; ++i) {
      int p = t + i * 256;
      int r = p >> 4, c = (p & 15) << 2;
      float4 v = *reinterpret_cast<const float4*>(
          &x[(size_t)(bm * 128 + r) * 1024 + kt + c]);
      ushort4 u;
      u.x = hfbits(v.x); u.y = hfbits(v.y); u.z = hfbits(v.z); u.w = hfbits(v.w);
      *reinterpret_cast<ushort4*>(&sA[r][c]) = u;
    }
#pragma unroll
    for (int i = 0; i < 4; ++i) {
      int p = t + i * 256;
      int r = p >> 3, c = (p & 7) << 3;
      uint4 v = *reinterpret_cast<const uint4*>(
          &wt[(size_t)(bn * 128 + r) * 1024 + kt + c]);
      *reinterpret_cast<uint4*>(&sB[r][c]) = v;
    }
    __syncthreads();
#pragma unroll
    for (int ks = 0; ks < 64; ks += 32) {
      half8 af[4], bb[4];
#pragma unroll
      for (int rs = 0; rs < 4; ++rs)
        af[rs] = *reinterpret_cast<const half8*>(&sA[wr * 64 + rs * 16 + lr][ks + g * 8]);
#pragma unroll
      for (int cs = 0; cs < 4; ++cs)
        bb[cs] = *reinterpret_cast<const half8*>(&sB[wc * 64 + cs * 16 + lr][ks + g * 8]);
#pragma unroll
      for (int rs = 0; rs < 4; ++rs)
#pragma unroll
        for (int cs = 0; cs < 4; ++cs)
          acc[rs][cs] = MFMA16(af[rs], bb[cs], acc[rs][cs]);
    }
    __syncthreads();
  }

  const int m0 = bm * 128 + wr * 64;
  const int n0 = bn * 128 + wc * 64;
  const int which = n0 >> 10;
  const int h = (n0 >> 6) & 15;
  ushort* dst = which == 0 ? qw : (which == 1 ? kw : vw);
  const float qsc = which == 0 ? 1.44269504088896f : 1.0f;  // log2(e) for Q
#pragma unroll
  for (int rs = 0; rs < 4; ++rs) {
#pragma unroll
    for (int r = 0; r < 4; ++r) {
      int m = m0 + rs * 16 + g * 4 + r;
      int b = m >> 11, s = m & 2047;
      ushort* rowp = dst + ((size_t)((b << 4) + h) * 2048 + s) * 64;
#pragma unroll
      for (int cs = 0; cs < 4; ++cs)
        rowp[cs * 16 + lr] = hfbits(acc[rs][cs][r] * qsc);
    }
  }
}

// ---------------------------------------------------------------------------
// Kernel 3: v [bh][2048][64] -> vt [bh][64][2048] (fp16 transpose)
// ---------------------------------------------------------------------------
__global__ __launch_bounds__(256) void k_vt(const ushort* __restrict__ vw,
                                            ushort* __restrict__ vt) {
  __shared__ ushort tile[64][72];
  const int t = threadIdx.x;
  const int s0 = blockIdx.x * 64, bh = blockIdx.y;
#pragma unroll
  for (int i = 0; i < 2; ++i) {
    int p = t + i * 256;
    int r = p >> 3, c = (p & 7) << 3;
    uint4 v = *reinterpret_cast<const uint4*>(
        &vw[((size_t)bh * 2048 + s0 + r) * 64 + c]);
    *reinterpret_cast<uint4*>(&tile[r][c]) = v;
  }
  __syncthreads();
#pragma unroll
  for (int i = 0; i < 2; ++i) {
    int p = t + i * 256;
    int dr = p >> 3, sc = (p & 7) << 3;
    union { ushort u[8]; uint4 v; } pk;
#pragma unroll
    for (int j = 0; j < 8; ++j) pk.u[j] = tile[sc + j][dr];
    *reinterpret_cast<uint4*>(&vt[((size_t)bh * 64 + dr) * 2048 + s0 + sc]) = pk.v;
  }
}

// ---------------------------------------------------------------------------
// Kernel 4: flash attention, 4 waves x 32 q-rows (two 16-row groups/wave).
// Round-2 counters: LDS read port was the serialized resource (each wave read
// the full 16KB K+V tile per iter). Now K/V fragments are loaded ONCE per
// wave-iter and feed MFMAs for BOTH q-groups -> LDS reads per S-element
// halve; MFMA:ds_read = 2:1. Mask is applied for free as the QK accumulator
// init (biasf = 0/-1e9, shift-invariant online softmax). XCD-clustered block
// decode: 4 bh per XCD -> K+V working set 2MB fits per-XCD L2.
// ---------------------------------------------------------------------------
__global__ __launch_bounds__(256) void k_attn(const ushort* __restrict__ qw,
                                              const ushort* __restrict__ kw,
                                              const ushort* __restrict__ vt,
                                              const float* __restrict__ biasf,
                                              float* __restrict__ out) {
  __shared__ __align__(16) ushort sK[2][64][64];   // 16 KB (2 bufs)
  __shared__ __align__(16) ushort sV[2][64][64];   // 16 KB (2 bufs)

  const int t = threadIdx.x;
  const int lane = t & 63, w = t >> 6;             // w in 0..3
  const int g = lane >> 4, lr = lane & 15;

  // XCD-clustered decode: id%8 = XCD (round-robin heuristic); 4 bh per XCD.
  const int id = blockIdx.x;                        // 0..511
  const int j = id >> 3;
  const int bh = (id & 7) * 4 + (j >> 4);
  const int qblk = j & 15;
  const int b = bh >> 4, h = bh & 15;

  // Q as B-operand for both groups: B col = lane&15 = q-row within group
  const int qrowA = qblk * 128 + w * 32 + lr;
  const ushort* qpA = qw + ((size_t)bh * 2048 + qrowA) * 64;
  const half8 qA0 = *reinterpret_cast<const half8*>(qpA + g * 8);
  const half8 qA1 = *reinterpret_cast<const half8*>(qpA + 32 + g * 8);
  const ushort* qpB = qpA + 16 * 64;
  const half8 qB0 = *reinterpret_cast<const half8*>(qpB + g * 8);
  const half8 qB1 = *reinterpret_cast<const half8*>(qpB + 32 + g * 8);

  const ushort* kbh = kw + (size_t)bh * 2048 * 64;
  const ushort* vbh = vt + (size_t)bh * 64 * 2048;
  const float* biasb = biasf + b * 2048;

  // permuted K row base for this lane's A-fragment row
  const int krbase = (lr >> 2) * 8 + (lr & 3);
  const int kswz = (((lr & 3) << 1) ^ (lr >> 2)) << 4;

  // staging: wave w stages chunks {2w,2w+1} (1KB each) of K and V tiles.
  const int c0 = w * 2;
  const int sr0 = c0 * 8 + (lane >> 3);
  const int sr1 = sr0 + 8;
  const int scb = (lane & 7) << 4;
  const int swz0 = scb ^ ((((sr0 & 3) << 1) ^ ((sr0 >> 3) & 3)) << 4);
  const int swz1 = scb ^ ((((sr1 & 3) << 1) ^ ((sr1 >> 3) & 3)) << 4);

  auto stage = [&](int bufi, int jtn) {
    gl16(kbh + (size_t)(jtn + sr0) * 64 + (swz0 >> 1), &sK[bufi][0][0] + (c0 + 0) * 512);
    gl16(kbh + (size_t)(jtn + sr1) * 64 + (swz1 >> 1), &sK[bufi][0][0] + (c0 + 1) * 512);
    gl16(vbh + (size_t)sr0 * 2048 + jtn + (swz0 >> 1), &sV[bufi][0][0] + (c0 + 0) * 512);
    gl16(vbh + (size_t)sr1 * 2048 + jtn + (swz1 >> 1), &sV[bufi][0][0] + (c0 + 1) * 512);
  };

  float mA = -__builtin_inff(), mB = -__builtin_inff();
  float lA = 0.f, lB = 0.f;
  f32x4 oA[4] = {}, oB[4] = {};

  // one softmax+PV step for one q-group (all indices static after inline)
  auto sm_step = [&](float (&st)[4][4], float& m_run, float& lsum,
                     f32x4 (&o)[4], const half8 (&vf0)[4], const half8 (&vf1)[4]) {
    // row max for q=lr: two 8-value max3 chains + combine + 2 shfl
    float ma = fmaxf(fmaxf(st[0][0], st[0][1]), st[0][2]);
    ma = fmaxf(fmaxf(ma, st[0][3]), st[1][0]);
    ma = fmaxf(fmaxf(ma, st[1][1]), st[1][2]);
    ma = fmaxf(ma, st[1][3]);
    float mb2 = fmaxf(fmaxf(st[2][0], st[2][1]), st[2][2]);
    mb2 = fmaxf(fmaxf(mb2, st[2][3]), st[3][0]);
    mb2 = fmaxf(fmaxf(mb2, st[3][1]), st[3][2]);
    mb2 = fmaxf(mb2, st[3][3]);
    float tmax = fmaxf(ma, mb2);
    tmax = fmaxf(tmax, __shfl_xor(tmax, 16));
    tmax = fmaxf(tmax, __shfl_xor(tmax, 32));

    // defer-max (T13, log2 units)
    if (!__all(tmax <= m_run + 8.f)) {
      const float mnew = fmaxf(m_run, tmax);
      const float sc = __builtin_amdgcn_exp2f(m_run - mnew);  // exp2(-inf)=0
      const float s0 = __shfl(sc, g * 4 + 0);
      const float s1 = __shfl(sc, g * 4 + 1);
      const float s2 = __shfl(sc, g * 4 + 2);
      const float s3 = __shfl(sc, g * 4 + 3);
#pragma unroll
      for (int dn = 0; dn < 4; ++dn) {
        o[dn][0] *= s0; o[dn][1] *= s1; o[dn][2] *= s2; o[dn][3] *= s3;
      }
      lsum *= sc;
      m_run = mnew;
    }

    float tsum = 0.f;
    unsigned int pd[8];
#pragma unroll
    for (int jn = 0; jn < 4; ++jn) {
      float p0 = __builtin_amdgcn_exp2f(st[jn][0] - m_run);
      float p1 = __builtin_amdgcn_exp2f(st[jn][1] - m_run);
      float p2 = __builtin_amdgcn_exp2f(st[jn][2] - m_run);
      float p3 = __builtin_amdgcn_exp2f(st[jn][3] - m_run);
      tsum += (p0 + p1) + (p2 + p3);
      pd[jn * 2 + 0] = __builtin_bit_cast(unsigned int, __builtin_amdgcn_cvt_pkrtz(p0, p1));
      pd[jn * 2 + 1] = __builtin_bit_cast(unsigned int, __builtin_amdgcn_cvt_pkrtz(p2, p3));
    }
    tsum += __shfl_xor(tsum, 16);
    tsum += __shfl_xor(tsum, 32);
    lsum += tsum;

    union { unsigned int u[4]; half8 hh; } pa0u, pa1u;
    pa0u.u[0] = pd[0]; pa0u.u[1] = pd[1]; pa0u.u[2] = pd[2]; pa0u.u[3] = pd[3];
    pa1u.u[0] = pd[4]; pa1u.u[1] = pd[5]; pa1u.u[2] = pd[6]; pa1u.u[3] = pd[7];

    __builtin_amdgcn_s_setprio(1);
#pragma unroll
    for (int dn = 0; dn < 4; ++dn) {
      o[dn] = MFMA16(pa0u.hh, vf0[dn], o[dn]);
      o[dn] = MFMA16(pa1u.hh, vf1[dn], o[dn]);
    }
    __builtin_amdgcn_s_setprio(0);
  };

  stage(0, 0);
  __syncthreads();
  int buf = 0;

  for (int jt = 0; jt < 2048; jt += 64) {
    if (jt + 64 < 2048) stage(buf ^ 1, jt + 64);

    // bias (mask) rows, hoisted; shared by both q-groups
    f32x4 bias4[4];
#pragma unroll
    for (int jn = 0; jn < 4; ++jn) {
      const int koff = (jn & 1) * 4 + (jn >> 1) * 32;
      bias4[jn] = *reinterpret_cast<const f32x4*>(biasb + jt + koff + g * 8);
    }

    // V fragments from LDS once, shared by both q-groups
    half8 vf0[4], vf1[4];
#pragma unroll
    for (int dn = 0; dn < 4; ++dn) {
      const int vr = dn * 16 + lr;
      const int vswz = ((((lr & 3) << 1) ^ ((2 * dn + (lr >> 3)) & 3)) << 4);
      const char* vrow = (const char*)&sV[buf][vr][0];
      vf0[dn] = *reinterpret_cast<const half8*>(vrow + ((16 * g) ^ vswz));
      vf1[dn] = *reinterpret_cast<const half8*>(vrow + ((64 + 16 * g) ^ vswz));
    }

    // K fragments once; QK^T for both groups (bias pre-loaded into C)
    float stA[4][4], stB[4][4];
#pragma unroll
    for (int jn = 0; jn < 4; ++jn) {
      const int koff = (jn & 1) * 4 + (jn >> 1) * 32;
      const int kr = koff + krbase;
      const char* krow = (const char*)&sK[buf][kr][0];
      half8 ka0 = *reinterpret_cast<const half8*>(krow + ((16 * g) ^ kswz));
      half8 ka1 = *reinterpret_cast<const half8*>(krow + ((64 + 16 * g) ^ kswz));
      f32x4 sA = bias4[jn];
      sA = MFMA16(ka0, qA0, sA);
      sA = MFMA16(ka1, qA1, sA);
      f32x4 sB = bias4[jn];
      sB = MFMA16(ka0, qB0, sB);
      sB = MFMA16(ka1, qB1, sB);
#pragma unroll
      for (int r = 0; r < 4; ++r) { stA[jn][r] = sA[r]; stB[jn][r] = sB[r]; }
    }

    sm_step(stA, mA, lA, oA, vf0, vf1);
    sm_step(stB, mB, lB, oB, vf0, vf1);

    __syncthreads();
    buf ^= 1;
  }

  // epilogue: both groups; 1/lsum redistributed q=lr -> q=g*4+r
  auto epi = [&](float lsum, f32x4 (&o)[4], int qbase) {
    const float rinv = 1.f / lsum;
    const float i0 = __shfl(rinv, g * 4 + 0);
    const float i1 = __shfl(rinv, g * 4 + 1);
    const float i2 = __shfl(rinv, g * 4 + 2);
    const float i3 = __shfl(rinv, g * 4 + 3);
    float* ob = out + ((size_t)b * 2048 + qbase) * 1024 + h * 64;
#pragma unroll
    for (int dn = 0; dn < 4; ++dn) {
      ob[0 * 1024 + dn * 16 + lr] = o[dn][0] * i0;
      ob[1 * 1024 + dn * 16 + lr] = o[dn][1] * i1;
      ob[2 * 1024 + dn * 16 + lr] = o[dn][2] * i2;
      ob[3 * 1024 + dn * 16 + lr] = o[dn][3] * i3;
    }
  };
  const int qbaseA = qblk * 128 + w * 32 + g * 4;
  epi(lA, oA, qbaseA);
  epi(lB, oB, qbaseA + 16);
}

// ---------------------------------------------------------------------------
extern "C" void kernel_launch(void* const* d_in, const int* in_sizes, int n_in,
                              void* d_out, int out_size, void* d_ws, size_t ws_size,
                              hipStream_t stream) {
  const float* x = (const float*)d_in[0];     // [2][2048][1024] f32
  const float* W = (const float*)d_in[1];     // [1024][3072] f32
  const int* mask = (const int*)d_in[2];      // [2][2048] i32
  float* out = (float*)d_out;                 // [2][2048][1024] f32
  char* ws = (char*)d_ws;

  ushort* wt = (ushort*)(ws);                                  // 6,291,456 B
  ushort* qw = (ushort*)(ws + 6291456);                        // 8,388,608 B
  ushort* kw = (ushort*)(ws + 6291456 + 8388608);              // 8,388,608 B
  ushort* vw = (ushort*)(ws + 6291456 + 2 * 8388608);          // 8,388,608 B
  ushort* vt = (ushort*)(ws + 6291456 + 3 * (size_t)8388608);  // 8,388,608 B
  float* biasf = (float*)(ws + 6291456 + 4 * (size_t)8388608); // 16,384 B

  k_wt<<<dim3(48, 16), 256, 0, stream>>>(W, wt, mask, biasf);
  k_gemm<<<dim3(24, 32), 256, 0, stream>>>(x, wt, qw, kw, vw);
  k_vt<<<dim3(32, 32), 256, 0, stream>>>(vw, vt);
  k_attn<<<dim3(512), 256, 0, stream>>>(qw, kw, vt, biasf, out);
}

// Round 4
// 116.229 us; speedup vs baseline: 1.1204x; 1.1204x over previous
//
#include <hip/hip_runtime.h>

typedef _Float16 half8 __attribute__((ext_vector_type(8)));
typedef float f32x4 __attribute__((ext_vector_type(4)));

#define MFMA16(a, b, c) __builtin_amdgcn_mfma_f32_16x16x32_f16((a), (b), (c), 0, 0, 0)

static __device__ __forceinline__ unsigned short hfbits(float f) {
  return __builtin_bit_cast(unsigned short, (_Float16)f);
}

// async global->LDS, 16B per lane; LDS dest = uniform base + lane*16
static __device__ __forceinline__ void gl16(const ushort* g, ushort* l) {
  __builtin_amdgcn_global_load_lds(
      (const __attribute__((address_space(1))) unsigned int*)g,
      (__attribute__((address_space(3))) unsigned int*)l, 16, 0, 0);
}

// ---------------------------------------------------------------------------
// Kernel 1: W [1024][3072] f32 -> Wt [3072][1024] fp16 (transposed + cast).
// Block (0,0) additionally converts mask[2][2048] i32 -> biasf f32 {0,-1e9}
// (consumed by k_attn as the QK MFMA accumulator init = free masking).
// ---------------------------------------------------------------------------
__global__ __launch_bounds__(256) void k_wt(const float* __restrict__ W,
                                            ushort* __restrict__ wt,
                                            const int* __restrict__ mask,
                                            float* __restrict__ biasf) {
  __shared__ ushort tile[64][72];
  const int t = threadIdx.x;
  const int n0 = blockIdx.x * 64, k0 = blockIdx.y * 64;
  if (blockIdx.x == 0 && blockIdx.y == 0) {
#pragma unroll
    for (int i = 0; i < 16; ++i) {
      int p = t + i * 256;
      biasf[p] = mask[p] ? 0.f : -1e9f;
    }
  }
#pragma unroll
  for (int i = 0; i < 4; ++i) {
    int p = t + i * 256;
    int r = p >> 4, c = (p & 15) << 2;
    float4 v = *reinterpret_cast<const float4*>(&W[(size_t)(k0 + r) * 3072 + n0 + c]);
    ushort4 u;
    u.x = hfbits(v.x); u.y = hfbits(v.y); u.z = hfbits(v.z); u.w = hfbits(v.w);
    *reinterpret_cast<ushort4*>(&tile[r][c]) = u;
  }
  __syncthreads();
#pragma unroll
  for (int i = 0; i < 4; ++i) {
    int p = t + i * 256;
    int rn = p >> 4, ck = (p & 15) << 2;
    ushort4 u;
    u.x = tile[ck + 0][rn]; u.y = tile[ck + 1][rn];
    u.z = tile[ck + 2][rn]; u.w = tile[ck + 3][rn];
    *reinterpret_cast<ushort4*>(&wt[(size_t)(n0 + rn) * 1024 + k0 + ck]) = u;
  }
}

// ---------------------------------------------------------------------------
// Kernel 2: qkv = x @ W.  Q outputs pre-scaled by log2(e) so k_attn can use
// exp2 directly (scale applied in f32 before the single f32->f16 round).
// ---------------------------------------------------------------------------
__global__ __launch_bounds__(256) void k_gemm(const float* __restrict__ x,
                                              const ushort* __restrict__ wt,
                                              ushort* __restrict__ qw,
                                              ushort* __restrict__ kw,
                                              ushort* __restrict__ vw) {
  __shared__ ushort sA[128][72];
  __shared__ ushort sB[128][72];
  const int t = threadIdx.x;
  const int lane = t & 63, w = t >> 6;
  const int g = lane >> 4, lr = lane & 15;
  const int wr = w >> 1, wc = w & 1;
  const int bn = blockIdx.x, bm = blockIdx.y;

  f32x4 acc[4][4] = {};

  for (int kt = 0; kt < 1024; kt += 64) {
#pragma unroll
    for (int i = 0; i < 8; ++i) {
      int p = t + i * 256;
      int r = p >> 4, c = (p & 15) << 2;
      float4 v = *reinterpret_cast<const float4*>(
          &x[(size_t)(bm * 128 + r) * 1024 + kt + c]);
      ushort4 u;
      u.x = hfbits(v.x); u.y = hfbits(v.y); u.z = hfbits(v.z); u.w = hfbits(v.w);
      *reinterpret_cast<ushort4*>(&sA[r][c]) = u;
    }
#pragma unroll
    for (int i = 0; i < 4; ++i) {
      int p = t + i * 256;
      int r = p >> 3, c = (p & 7) << 3;
      uint4 v = *reinterpret_cast<const uint4*>(
          &wt[(size_t)(bn * 128 + r) * 1024 + kt + c]);
      *reinterpret_cast<uint4*>(&sB[r][c]) = v;
    }
    __syncthreads();
#pragma unroll
    for (int ks = 0; ks < 64; ks += 32) {
      half8 af[4], bb[4];
#pragma unroll
      for (int rs = 0; rs < 4; ++rs)
        af[rs] = *reinterpret_cast<const half8*>(&sA[wr * 64 + rs * 16 + lr][ks + g * 8]);
#pragma unroll
      for (int cs = 0; cs < 4; ++cs)
        bb[cs] = *reinterpret_cast<const half8*>(&sB[wc * 64 + cs * 16 + lr][ks + g * 8]);
#pragma unroll
      for (int rs = 0; rs < 4; ++rs)
#pragma unroll
        for (int cs = 0; cs < 4; ++cs)
          acc[rs][cs] = MFMA16(af[rs], bb[cs], acc[rs][cs]);
    }
    __syncthreads();
  }

  const int m0 = bm * 128 + wr * 64;
  const int n0 = bn * 128 + wc * 64;
  const int which = n0 >> 10;
  const int h = (n0 >> 6) & 15;
  ushort* dst = which == 0 ? qw : (which == 1 ? kw : vw);
  const float qsc = which == 0 ? 1.44269504088896f : 1.0f;  // log2(e) for Q
#pragma unroll
  for (int rs = 0; rs < 4; ++rs) {
#pragma unroll
    for (int r = 0; r < 4; ++r) {
      int m = m0 + rs * 16 + g * 4 + r;
      int b = m >> 11, s = m & 2047;
      ushort* rowp = dst + ((size_t)((b << 4) + h) * 2048 + s) * 64;
#pragma unroll
      for (int cs = 0; cs < 4; ++cs)
        rowp[cs * 16 + lr] = hfbits(acc[rs][cs][r] * qsc);
    }
  }
}

// ---------------------------------------------------------------------------
// Kernel 3: v [bh][2048][64] -> vt [bh][64][2048] (fp16 transpose)
// ---------------------------------------------------------------------------
__global__ __launch_bounds__(256) void k_vt(const ushort* __restrict__ vw,
                                            ushort* __restrict__ vt) {
  __shared__ ushort tile[64][72];
  const int t = threadIdx.x;
  const int s0 = blockIdx.x * 64, bh = blockIdx.y;
#pragma unroll
  for (int i = 0; i < 2; ++i) {
    int p = t + i * 256;
    int r = p >> 3, c = (p & 7) << 3;
    uint4 v = *reinterpret_cast<const uint4*>(
        &vw[((size_t)bh * 2048 + s0 + r) * 64 + c]);
    *reinterpret_cast<uint4*>(&tile[r][c]) = v;
  }
  __syncthreads();
#pragma unroll
  for (int i = 0; i < 2; ++i) {
    int p = t + i * 256;
    int dr = p >> 3, sc = (p & 7) << 3;
    union { ushort u[8]; uint4 v; } pk;
#pragma unroll
    for (int j = 0; j < 8; ++j) pk.u[j] = tile[sc + j][dr];
    *reinterpret_cast<uint4*>(&vt[((size_t)bh * 64 + dr) * 2048 + s0 + sc]) = pk.v;
  }
}

// ---------------------------------------------------------------------------
// Kernel 4: flash attention, 8 waves / 512 threads, 16 q-rows per wave.
// R3 lesson: VALUBusy x dur (~35us) is the invariant -> kernel is VALU-work
// + dep-chain bound; occupancy (16 waves/CU) is what keeps the VALU fed, so
// the R2 shape is restored.  VALU diet vs R2:
//  - mask applied as QK accumulator init (biasf {0,-1e9}): no cndmask/int ld
//  - denominator = ones-column MFMA: oden[r] = sum_k P[q=g*4+r][k] lands in
//    the SAME layout as o -> no per-iter sum/shfl, no epilogue shfl at all;
//    rescale multiplies apply to oden exactly like o (shift-invariance).
//  - row max via fmaxf chains (fuse to v_max3_f32)
// XCD-clustered decode kept (FETCH 69.7 -> 12.4 MB in R3).
// ---------------------------------------------------------------------------
__global__ __launch_bounds__(512) void k_attn(const ushort* __restrict__ qw,
                                              const ushort* __restrict__ kw,
                                              const ushort* __restrict__ vt,
                                              const float* __restrict__ biasf,
                                              float* __restrict__ out) {
  __shared__ __align__(16) ushort sK[2][64][64];   // 16 KB (2 bufs)
  __shared__ __align__(16) ushort sV[2][64][64];   // 16 KB (2 bufs)

  const int t = threadIdx.x;
  const int lane = t & 63, w = t >> 6;             // w in 0..7
  const int g = lane >> 4, lr = lane & 15;

  // XCD-clustered decode: id%8 = XCD; 4 bh x 16 qblk per XCD.
  const int id = blockIdx.x;                        // 0..511
  const int j = id >> 3;
  const int bh = (id & 7) * 4 + (j >> 4);
  const int qblk = j & 15;
  const int b = bh >> 4, h = bh & 15;

  // Q as B-operand: B col = lane&15 = q-row (within wave's 16 rows)
  const int qrow = qblk * 128 + w * 16 + lr;
  const ushort* qp = qw + ((size_t)bh * 2048 + qrow) * 64;
  const half8 qb0 = *reinterpret_cast<const half8*>(qp + g * 8);
  const half8 qb1 = *reinterpret_cast<const half8*>(qp + 32 + g * 8);

  const ushort* kbh = kw + (size_t)bh * 2048 * 64;
  const ushort* vbh = vt + (size_t)bh * 64 * 2048;
  const float* biasb = biasf + b * 2048;

  // permuted K row base for this lane's A-fragment row
  const int krbase = (lr >> 2) * 8 + (lr & 3);
  const int kswz = (((lr & 3) << 1) ^ (lr >> 2)) << 4;

  // staging: wave w stages chunk w (1 KB) of both K and V tiles.
  const int sr0 = w * 8 + (lane >> 3);
  const int scb = (lane & 7) << 4;
  const int swz0 = scb ^ ((((sr0 & 3) << 1) ^ ((sr0 >> 3) & 3)) << 4);

  auto stage = [&](int bufi, int jtn) {
    gl16(kbh + (size_t)(jtn + sr0) * 64 + (swz0 >> 1), &sK[bufi][0][0] + w * 512);
    gl16(vbh + (size_t)sr0 * 2048 + jtn + (swz0 >> 1), &sV[bufi][0][0] + w * 512);
  };

  const half8 vones = {(_Float16)1.f, (_Float16)1.f, (_Float16)1.f, (_Float16)1.f,
                       (_Float16)1.f, (_Float16)1.f, (_Float16)1.f, (_Float16)1.f};

  float m_run = -__builtin_inff();   // running max (log2 units) for q = lr
  f32x4 o[4] = {};                   // o[dn][r]: q = g*4+r, d = dn*16+lr
  f32x4 oden = {};                   // oden[r]: sum_k P[q=g*4+r][k]

  stage(0, 0);
  __syncthreads();                   // drains vmcnt(0): tile 0 landed
  int buf = 0;

  for (int jt = 0; jt < 2048; jt += 64) {
    // ---- issue next-tile prefetch first (in flight across the whole tile)
    if (jt + 64 < 2048) stage(buf ^ 1, jt + 64);

    // ---- bias (mask) rows, as MFMA C-init: bias4[jn][r] = bias[k=koff+g*8+r]
    f32x4 bias4[4];
#pragma unroll
    for (int jn = 0; jn < 4; ++jn) {
      const int koff = (jn & 1) * 4 + (jn >> 1) * 32;
      bias4[jn] = *reinterpret_cast<const f32x4*>(biasb + jt + koff + g * 8);
    }

    // ---- V fragments from LDS (independent of QK path)
    half8 vf0[4], vf1[4];
#pragma unroll
    for (int dn = 0; dn < 4; ++dn) {
      const int vr = dn * 16 + lr;
      const int vswz = ((((lr & 3) << 1) ^ ((2 * dn + (lr >> 3)) & 3)) << 4);
      const char* vrow = (const char*)&sV[buf][vr][0];
      vf0[dn] = *reinterpret_cast<const half8*>(vrow + ((16 * g) ^ vswz));
      vf1[dn] = *reinterpret_cast<const half8*>(vrow + ((64 + 16 * g) ^ vswz));
    }

    // ---- S^T via permuted-K MFMAs (mask pre-added via C): st[jn][r] =
    //      S[q=lr][k=koff+g*8+r] + bias
    float st[4][4];
#pragma unroll
    for (int jn = 0; jn < 4; ++jn) {
      const int koff = (jn & 1) * 4 + (jn >> 1) * 32;
      const int kr = koff + krbase;
      const char* krow = (const char*)&sK[buf][kr][0];
      half8 ka0 = *reinterpret_cast<const half8*>(krow + ((16 * g) ^ kswz));
      half8 ka1 = *reinterpret_cast<const half8*>(krow + ((64 + 16 * g) ^ kswz));
      f32x4 s4 = bias4[jn];
      s4 = MFMA16(ka0, qb0, s4);
      s4 = MFMA16(ka1, qb1, s4);
#pragma unroll
      for (int r = 0; r < 4; ++r) st[jn][r] = s4[r];
    }

    // ---- row max for q=lr (fmax chains -> v_max3) + 2 shfl
    float ma = fmaxf(fmaxf(st[0][0], st[0][1]), st[0][2]);
    ma = fmaxf(fmaxf(ma, st[0][3]), st[1][0]);
    ma = fmaxf(fmaxf(ma, st[1][1]), st[1][2]);
    ma = fmaxf(ma, st[1][3]);
    float mb2 = fmaxf(fmaxf(st[2][0], st[2][1]), st[2][2]);
    mb2 = fmaxf(fmaxf(mb2, st[2][3]), st[3][0]);
    mb2 = fmaxf(fmaxf(mb2, st[3][1]), st[3][2]);
    mb2 = fmaxf(mb2, st[3][3]);
    float tmax = fmaxf(ma, mb2);
    tmax = fmaxf(tmax, __shfl_xor(tmax, 16));
    tmax = fmaxf(tmax, __shfl_xor(tmax, 32));

    // ---- defer-max (T13, log2 units): skip rescale when max barely grows
    if (!__all(tmax <= m_run + 8.f)) {
      const float mnew = fmaxf(m_run, tmax);
      const float sc = __builtin_amdgcn_exp2f(m_run - mnew);  // exp2(-inf)=0
      const float s0 = __shfl(sc, g * 4 + 0);
      const float s1 = __shfl(sc, g * 4 + 1);
      const float s2 = __shfl(sc, g * 4 + 2);
      const float s3 = __shfl(sc, g * 4 + 3);
#pragma unroll
      for (int dn = 0; dn < 4; ++dn) {
        o[dn][0] *= s0; o[dn][1] *= s1; o[dn][2] *= s2; o[dn][3] *= s3;
      }
      oden[0] *= s0; oden[1] *= s1; oden[2] *= s2; oden[3] *= s3;
      m_run = mnew;
    }

    // ---- P = exp2(S - m): pack in-register into PV A-fragments
    unsigned int pd[8];
#pragma unroll
    for (int jn = 0; jn < 4; ++jn) {
      float p0 = __builtin_amdgcn_exp2f(st[jn][0] - m_run);
      float p1 = __builtin_amdgcn_exp2f(st[jn][1] - m_run);
      float p2 = __builtin_amdgcn_exp2f(st[jn][2] - m_run);
      float p3 = __builtin_amdgcn_exp2f(st[jn][3] - m_run);
      pd[jn * 2 + 0] = __builtin_bit_cast(unsigned int, __builtin_amdgcn_cvt_pkrtz(p0, p1));
      pd[jn * 2 + 1] = __builtin_bit_cast(unsigned int, __builtin_amdgcn_cvt_pkrtz(p2, p3));
    }

    union { unsigned int u[4]; half8 h; } pa0u, pa1u;
    pa0u.u[0] = pd[0]; pa0u.u[1] = pd[1]; pa0u.u[2] = pd[2]; pa0u.u[3] = pd[3];
    pa1u.u[0] = pd[4]; pa1u.u[1] = pd[5]; pa1u.u[2] = pd[6]; pa1u.u[3] = pd[7];

    __builtin_amdgcn_s_setprio(1);
#pragma unroll
    for (int dn = 0; dn < 4; ++dn) {
      o[dn] = MFMA16(pa0u.h, vf0[dn], o[dn]);
      o[dn] = MFMA16(pa1u.h, vf1[dn], o[dn]);
    }
    // denominator: ones-column MFMA (same rescale path as o)
    oden = MFMA16(pa0u.h, vones, oden);
    oden = MFMA16(pa1u.h, vones, oden);
    __builtin_amdgcn_s_setprio(0);

    // one barrier per tile: drains vmcnt(0) (prefetch landed) and protects buf
    __syncthreads();
    buf ^= 1;
  }

  // ---- epilogue: oden is already in the o layout -> no shuffles
  const float i0 = 1.f / oden[0];
  const float i1 = 1.f / oden[1];
  const float i2 = 1.f / oden[2];
  const float i3 = 1.f / oden[3];
  const int s0r = qblk * 128 + w * 16 + g * 4;
  float* ob = out + ((size_t)b * 2048 + s0r) * 1024 + h * 64;
#pragma unroll
  for (int dn = 0; dn < 4; ++dn) {
    ob[0 * 1024 + dn * 16 + lr] = o[dn][0] * i0;
    ob[1 * 1024 + dn * 16 + lr] = o[dn][1] * i1;
    ob[2 * 1024 + dn * 16 + lr] = o[dn][2] * i2;
    ob[3 * 1024 + dn * 16 + lr] = o[dn][3] * i3;
  }
}

// ---------------------------------------------------------------------------
extern "C" void kernel_launch(void* const* d_in, const int* in_sizes, int n_in,
                              void* d_out, int out_size, void* d_ws, size_t ws_size,
                              hipStream_t stream) {
  const float* x = (const float*)d_in[0];     // [2][2048][1024] f32
  const float* W = (const float*)d_in[1];     // [1024][3072] f32
  const int* mask = (const int*)d_in[2];      // [2][2048] i32
  float* out = (float*)d_out;                 // [2][2048][1024] f32
  char* ws = (char*)d_ws;

  ushort* wt = (ushort*)(ws);                                  // 6,291,456 B
  ushort* qw = (ushort*)(ws + 6291456);                        // 8,388,608 B
  ushort* kw = (ushort*)(ws + 6291456 + 8388608);              // 8,388,608 B
  ushort* vw = (ushort*)(ws + 6291456 + 2 * 8388608);          // 8,388,608 B
  ushort* vt = (ushort*)(ws + 6291456 + 3 * (size_t)8388608);  // 8,388,608 B
  float* biasf = (float*)(ws + 6291456 + 4 * (size_t)8388608); // 16,384 B

  k_wt<<<dim3(48, 16), 256, 0, stream>>>(W, wt, mask, biasf);
  k_gemm<<<dim3(24, 32), 256, 0, stream>>>(x, wt, qw, kw, vw);
  k_vt<<<dim3(32, 32), 256, 0, stream>>>(vw, vt);
  k_attn<<<dim3(512), 512, 0, stream>>>(qw, kw, vt, biasf, out);
}

// Round 5
// 116.225 us; speedup vs baseline: 1.1205x; 1.0000x over previous
//
#include <hip/hip_runtime.h>

typedef _Float16 half8 __attribute__((ext_vector_type(8)));
typedef float f32x4 __attribute__((ext_vector_type(4)));

#define MFMA16(a, b, c) __builtin_amdgcn_mfma_f32_16x16x32_f16((a), (b), (c), 0, 0, 0)

static __device__ __forceinline__ unsigned short hfbits(float f) {
  return __builtin_bit_cast(unsigned short, (_Float16)f);
}

// async global->LDS, 16B per lane; LDS dest = uniform base + lane*16
static __device__ __forceinline__ void gl16(const ushort* g, ushort* l) {
  __builtin_amdgcn_global_load_lds(
      (const __attribute__((address_space(1))) unsigned int*)g,
      (__attribute__((address_space(3))) unsigned int*)l, 16, 0, 0);
}

// ---------------------------------------------------------------------------
// Kernel 0: x [2][2048][1024] f32 -> xh fp16 (cast once; k_gemm then reads
// half the bytes and does zero cvt VALU work).  Block 0 also builds
// biasf {0,-1e9} from mask (consumed as QK MFMA accumulator init).
// ---------------------------------------------------------------------------
__global__ __launch_bounds__(256) void k_xh(const float* __restrict__ x,
                                            ushort* __restrict__ xh,
                                            const int* __restrict__ mask,
                                            float* __restrict__ biasf) {
  const size_t p = ((size_t)blockIdx.x * 256 + threadIdx.x) * 8;
  float4 a = *reinterpret_cast<const float4*>(x + p);
  float4 b = *reinterpret_cast<const float4*>(x + p + 4);
  union { ushort u[8]; uint4 v; } pk;
  pk.u[0] = hfbits(a.x); pk.u[1] = hfbits(a.y);
  pk.u[2] = hfbits(a.z); pk.u[3] = hfbits(a.w);
  pk.u[4] = hfbits(b.x); pk.u[5] = hfbits(b.y);
  pk.u[6] = hfbits(b.z); pk.u[7] = hfbits(b.w);
  *reinterpret_cast<uint4*>(xh + p) = pk.v;
  if (blockIdx.x == 0) {
#pragma unroll
    for (int i = 0; i < 16; ++i) {
      int q = threadIdx.x + i * 256;
      biasf[q] = mask[q] ? 0.f : -1e9f;
    }
  }
}

// ---------------------------------------------------------------------------
// Kernel 1: W [1024][3072] f32 -> Wt [3072][1024] fp16 (transposed + cast)
// ---------------------------------------------------------------------------
__global__ __launch_bounds__(256) void k_wt(const float* __restrict__ W,
                                            ushort* __restrict__ wt) {
  __shared__ ushort tile[64][72];
  const int t = threadIdx.x;
  const int n0 = blockIdx.x * 64, k0 = blockIdx.y * 64;
#pragma unroll
  for (int i = 0; i < 4; ++i) {
    int p = t + i * 256;
    int r = p >> 4, c = (p & 15) << 2;
    float4 v = *reinterpret_cast<const float4*>(&W[(size_t)(k0 + r) * 3072 + n0 + c]);
    ushort4 u;
    u.x = hfbits(v.x); u.y = hfbits(v.y); u.z = hfbits(v.z); u.w = hfbits(v.w);
    *reinterpret_cast<ushort4*>(&tile[r][c]) = u;
  }
  __syncthreads();
#pragma unroll
  for (int i = 0; i < 4; ++i) {
    int p = t + i * 256;
    int rn = p >> 4, ck = (p & 15) << 2;
    ushort4 u;
    u.x = tile[ck + 0][rn]; u.y = tile[ck + 1][rn];
    u.z = tile[ck + 2][rn]; u.w = tile[ck + 3][rn];
    *reinterpret_cast<ushort4*>(&wt[(size_t)(n0 + rn) * 1024 + k0 + ck]) = u;
  }
}

// ---------------------------------------------------------------------------
// Kernel 2: qkv = xh @ W (both fp16, m97-style).  Staging is pure
// global_load_lds width-16 into LINEAR 32KB LDS; bank conflicts on the
// fragment ds_reads are handled by the XOR slot-swizzle involution
// s(r) = ((r&3)<<1)^((r>>3)&3) applied to the SOURCE column at stage time
// and to the byte offset at read time (rule-21 both-sides pattern, same as
// k_attn).  2-barrier K-loop; 3 blocks/CU provide the latency overlap.
// Q outputs pre-scaled by log2(e) (exp2 path in k_attn).
// ---------------------------------------------------------------------------
__global__ __launch_bounds__(256) void k_gemm(const ushort* __restrict__ xh,
                                              const ushort* __restrict__ wt,
                                              ushort* __restrict__ qw,
                                              ushort* __restrict__ kw,
                                              ushort* __restrict__ vw) {
  __shared__ __align__(16) ushort sA[128 * 64];   // 16 KB linear, swizzled
  __shared__ __align__(16) ushort sB[128 * 64];   // 16 KB linear, swizzled
  const int t = threadIdx.x;
  const int lane = t & 63, w = t >> 6;
  const int g = lane >> 4, lr = lane & 15;
  const int wr = w >> 1, wc = w & 1;
  const int bn = blockIdx.x, bm = blockIdx.y;

  // staging geometry: wave w stages chunks 4w..4w+3 (1KB each) of A and B.
  // chunk c: LDS row r = c*8 + (lane>>3), slot lane&7; source slot ^= s(r).
  int srow[4], soff[4];
#pragma unroll
  for (int i = 0; i < 4; ++i) {
    const int c = 4 * w + i;
    const int r = c * 8 + (lane >> 3);
    const int sl = (lane & 7) ^ (((r & 3) << 1) ^ ((r >> 3) & 3));
    srow[i] = r;
    soff[i] = sl * 8;      // ushort offset within the 64-col row
  }

  // read-side swizzle per fragment row (hoisted: depends on lr only)
  int raswz[4], rbswz[4];
#pragma unroll
  for (int rs = 0; rs < 4; ++rs) {
    const int ra = wr * 64 + rs * 16 + lr;
    raswz[rs] = ((((ra & 3) << 1) ^ ((ra >> 3) & 3)) << 4);
    const int rb = wc * 64 + rs * 16 + lr;
    rbswz[rs] = ((((rb & 3) << 1) ^ ((rb >> 3) & 3)) << 4);
  }

  f32x4 acc[4][4] = {};

  for (int kt = 0; kt < 1024; kt += 64) {
#pragma unroll
    for (int i = 0; i < 4; ++i) {
      gl16(xh + (size_t)(bm * 128 + srow[i]) * 1024 + kt + soff[i],
           sA + (4 * w + i) * 512);
      gl16(wt + (size_t)(bn * 128 + srow[i]) * 1024 + kt + soff[i],
           sB + (4 * w + i) * 512);
    }
    __syncthreads();   // drains vmcnt: tile landed
#pragma unroll
    for (int ks = 0; ks < 64; ks += 32) {
      half8 af[4], bb[4];
#pragma unroll
      for (int rs = 0; rs < 4; ++rs) {
        const int ra = wr * 64 + rs * 16 + lr;
        af[rs] = *reinterpret_cast<const half8*>(
            (const char*)sA + ra * 128 + ((16 * g + 2 * ks) ^ raswz[rs]));
      }
#pragma unroll
      for (int cs = 0; cs < 4; ++cs) {
        const int rb = wc * 64 + cs * 16 + lr;
        bb[cs] = *reinterpret_cast<const half8*>(
            (const char*)sB + rb * 128 + ((16 * g + 2 * ks) ^ rbswz[cs]));
      }
#pragma unroll
      for (int rs = 0; rs < 4; ++rs)
#pragma unroll
        for (int cs = 0; cs < 4; ++cs)
          acc[rs][cs] = MFMA16(af[rs], bb[cs], acc[rs][cs]);
    }
    __syncthreads();   // all waves done reading before next stage overwrites
  }

  const int m0 = bm * 128 + wr * 64;
  const int n0 = bn * 128 + wc * 64;
  const int which = n0 >> 10;
  const int h = (n0 >> 6) & 15;
  ushort* dst = which == 0 ? qw : (which == 1 ? kw : vw);
  const float qsc = which == 0 ? 1.44269504088896f : 1.0f;  // log2(e) for Q
#pragma unroll
  for (int rs = 0; rs < 4; ++rs) {
#pragma unroll
    for (int r = 0; r < 4; ++r) {
      int m = m0 + rs * 16 + g * 4 + r;
      int b = m >> 11, s = m & 2047;
      ushort* rowp = dst + ((size_t)((b << 4) + h) * 2048 + s) * 64;
#pragma unroll
      for (int cs = 0; cs < 4; ++cs)
        rowp[cs * 16 + lr] = hfbits(acc[rs][cs][r] * qsc);
    }
  }
}

// ---------------------------------------------------------------------------
// Kernel 3: v [bh][2048][64] -> vt [bh][64][2048] (fp16 transpose)
// ---------------------------------------------------------------------------
__global__ __launch_bounds__(256) void k_vt(const ushort* __restrict__ vw,
                                            ushort* __restrict__ vt) {
  __shared__ ushort tile[64][72];
  const int t = threadIdx.x;
  const int s0 = blockIdx.x * 64, bh = blockIdx.y;
#pragma unroll
  for (int i = 0; i < 2; ++i) {
    int p = t + i * 256;
    int r = p >> 3, c = (p & 7) << 3;
    uint4 v = *reinterpret_cast<const uint4*>(
        &vw[((size_t)bh * 2048 + s0 + r) * 64 + c]);
    *reinterpret_cast<uint4*>(&tile[r][c]) = v;
  }
  __syncthreads();
#pragma unroll
  for (int i = 0; i < 2; ++i) {
    int p = t + i * 256;
    int dr = p >> 3, sc = (p & 7) << 3;
    union { ushort u[8]; uint4 v; } pk;
#pragma unroll
    for (int j = 0; j < 8; ++j) pk.u[j] = tile[sc + j][dr];
    *reinterpret_cast<uint4*>(&vt[((size_t)bh * 64 + dr) * 2048 + s0 + sc]) = pk.v;
  }
}

// ---------------------------------------------------------------------------
// Kernel 4: flash attention (unchanged from R4: 8 waves, bias-in-C, ones-
// column denominator MFMA, exp2, defer-max, XCD-clustered decode).
// ---------------------------------------------------------------------------
__global__ __launch_bounds__(512) void k_attn(const ushort* __restrict__ qw,
                                              const ushort* __restrict__ kw,
                                              const ushort* __restrict__ vt,
                                              const float* __restrict__ biasf,
                                              float* __restrict__ out) {
  __shared__ __align__(16) ushort sK[2][64][64];   // 16 KB (2 bufs)
  __shared__ __align__(16) ushort sV[2][64][64];   // 16 KB (2 bufs)

  const int t = threadIdx.x;
  const int lane = t & 63, w = t >> 6;             // w in 0..7
  const int g = lane >> 4, lr = lane & 15;

  // XCD-clustered decode: id%8 = XCD; 4 bh x 16 qblk per XCD.
  const int id = blockIdx.x;                        // 0..511
  const int j = id >> 3;
  const int bh = (id & 7) * 4 + (j >> 4);
  const int qblk = j & 15;
  const int b = bh >> 4, h = bh & 15;

  // Q as B-operand: B col = lane&15 = q-row (within wave's 16 rows)
  const int qrow = qblk * 128 + w * 16 + lr;
  const ushort* qp = qw + ((size_t)bh * 2048 + qrow) * 64;
  const half8 qb0 = *reinterpret_cast<const half8*>(qp + g * 8);
  const half8 qb1 = *reinterpret_cast<const half8*>(qp + 32 + g * 8);

  const ushort* kbh = kw + (size_t)bh * 2048 * 64;
  const ushort* vbh = vt + (size_t)bh * 64 * 2048;
  const float* biasb = biasf + b * 2048;

  // permuted K row base for this lane's A-fragment row
  const int krbase = (lr >> 2) * 8 + (lr & 3);
  const int kswz = (((lr & 3) << 1) ^ (lr >> 2)) << 4;

  // staging: wave w stages chunk w (1 KB) of both K and V tiles.
  const int sr0 = w * 8 + (lane >> 3);
  const int scb = (lane & 7) << 4;
  const int swz0 = scb ^ ((((sr0 & 3) << 1) ^ ((sr0 >> 3) & 3)) << 4);

  auto stage = [&](int bufi, int jtn) {
    gl16(kbh + (size_t)(jtn + sr0) * 64 + (swz0 >> 1), &sK[bufi][0][0] + w * 512);
    gl16(vbh + (size_t)sr0 * 2048 + jtn + (swz0 >> 1), &sV[bufi][0][0] + w * 512);
  };

  const half8 vones = {(_Float16)1.f, (_Float16)1.f, (_Float16)1.f, (_Float16)1.f,
                       (_Float16)1.f, (_Float16)1.f, (_Float16)1.f, (_Float16)1.f};

  float m_run = -__builtin_inff();   // running max (log2 units) for q = lr
  f32x4 o[4] = {};                   // o[dn][r]: q = g*4+r, d = dn*16+lr
  f32x4 oden = {};                   // oden[r]: sum_k P[q=g*4+r][k]

  stage(0, 0);
  __syncthreads();                   // drains vmcnt(0): tile 0 landed
  int buf = 0;

  for (int jt = 0; jt < 2048; jt += 64) {
    if (jt + 64 < 2048) stage(buf ^ 1, jt + 64);

    f32x4 bias4[4];
#pragma unroll
    for (int jn = 0; jn < 4; ++jn) {
      const int koff = (jn & 1) * 4 + (jn >> 1) * 32;
      bias4[jn] = *reinterpret_cast<const f32x4*>(biasb + jt + koff + g * 8);
    }

    half8 vf0[4], vf1[4];
#pragma unroll
    for (int dn = 0; dn < 4; ++dn) {
      const int vr = dn * 16 + lr;
      const int vswz = ((((lr & 3) << 1) ^ ((2 * dn + (lr >> 3)) & 3)) << 4);
      const char* vrow = (const char*)&sV[buf][vr][0];
      vf0[dn] = *reinterpret_cast<const half8*>(vrow + ((16 * g) ^ vswz));
      vf1[dn] = *reinterpret_cast<const half8*>(vrow + ((64 + 16 * g) ^ vswz));
    }

    float st[4][4];
#pragma unroll
    for (int jn = 0; jn < 4; ++jn) {
      const int koff = (jn & 1) * 4 + (jn >> 1) * 32;
      const int kr = koff + krbase;
      const char* krow = (const char*)&sK[buf][kr][0];
      half8 ka0 = *reinterpret_cast<const half8*>(krow + ((16 * g) ^ kswz));
      half8 ka1 = *reinterpret_cast<const half8*>(krow + ((64 + 16 * g) ^ kswz));
      f32x4 s4 = bias4[jn];
      s4 = MFMA16(ka0, qb0, s4);
      s4 = MFMA16(ka1, qb1, s4);
#pragma unroll
      for (int r = 0; r < 4; ++r) st[jn][r] = s4[r];
    }

    float ma = fmaxf(fmaxf(st[0][0], st[0][1]), st[0][2]);
    ma = fmaxf(fmaxf(ma, st[0][3]), st[1][0]);
    ma = fmaxf(fmaxf(ma, st[1][1]), st[1][2]);
    ma = fmaxf(ma, st[1][3]);
    float mb2 = fmaxf(fmaxf(st[2][0], st[2][1]), st[2][2]);
    mb2 = fmaxf(fmaxf(mb2, st[2][3]), st[3][0]);
    mb2 = fmaxf(fmaxf(mb2, st[3][1]), st[3][2]);
    mb2 = fmaxf(mb2, st[3][3]);
    float tmax = fmaxf(ma, mb2);
    tmax = fmaxf(tmax, __shfl_xor(tmax, 16));
    tmax = fmaxf(tmax, __shfl_xor(tmax, 32));

    if (!__all(tmax <= m_run + 8.f)) {
      const float mnew = fmaxf(m_run, tmax);
      const float sc = __builtin_amdgcn_exp2f(m_run - mnew);  // exp2(-inf)=0
      const float s0 = __shfl(sc, g * 4 + 0);
      const float s1 = __shfl(sc, g * 4 + 1);
      const float s2 = __shfl(sc, g * 4 + 2);
      const float s3 = __shfl(sc, g * 4 + 3);
#pragma unroll
      for (int dn = 0; dn < 4; ++dn) {
        o[dn][0] *= s0; o[dn][1] *= s1; o[dn][2] *= s2; o[dn][3] *= s3;
      }
      oden[0] *= s0; oden[1] *= s1; oden[2] *= s2; oden[3] *= s3;
      m_run = mnew;
    }

    unsigned int pd[8];
#pragma unroll
    for (int jn = 0; jn < 4; ++jn) {
      float p0 = __builtin_amdgcn_exp2f(st[jn][0] - m_run);
      float p1 = __builtin_amdgcn_exp2f(st[jn][1] - m_run);
      float p2 = __builtin_amdgcn_exp2f(st[jn][2] - m_run);
      float p3 = __builtin_amdgcn_exp2f(st[jn][3] - m_run);
      pd[jn * 2 + 0] = __builtin_bit_cast(unsigned int, __builtin_amdgcn_cvt_pkrtz(p0, p1));
      pd[jn * 2 + 1] = __builtin_bit_cast(unsigned int, __builtin_amdgcn_cvt_pkrtz(p2, p3));
    }

    union { unsigned int u[4]; half8 h; } pa0u, pa1u;
    pa0u.u[0] = pd[0]; pa0u.u[1] = pd[1]; pa0u.u[2] = pd[2]; pa0u.u[3] = pd[3];
    pa1u.u[0] = pd[4]; pa1u.u[1] = pd[5]; pa1u.u[2] = pd[6]; pa1u.u[3] = pd[7];

    __builtin_amdgcn_s_setprio(1);
#pragma unroll
    for (int dn = 0; dn < 4; ++dn) {
      o[dn] = MFMA16(pa0u.h, vf0[dn], o[dn]);
      o[dn] = MFMA16(pa1u.h, vf1[dn], o[dn]);
    }
    oden = MFMA16(pa0u.h, vones, oden);
    oden = MFMA16(pa1u.h, vones, oden);
    __builtin_amdgcn_s_setprio(0);

    __syncthreads();
    buf ^= 1;
  }

  const float i0 = 1.f / oden[0];
  const float i1 = 1.f / oden[1];
  const float i2 = 1.f / oden[2];
  const float i3 = 1.f / oden[3];
  const int s0r = qblk * 128 + w * 16 + g * 4;
  float* ob = out + ((size_t)b * 2048 + s0r) * 1024 + h * 64;
#pragma unroll
  for (int dn = 0; dn < 4; ++dn) {
    ob[0 * 1024 + dn * 16 + lr] = o[dn][0] * i0;
    ob[1 * 1024 + dn * 16 + lr] = o[dn][1] * i1;
    ob[2 * 1024 + dn * 16 + lr] = o[dn][2] * i2;
    ob[3 * 1024 + dn * 16 + lr] = o[dn][3] * i3;
  }
}

// ---------------------------------------------------------------------------
extern "C" void kernel_launch(void* const* d_in, const int* in_sizes, int n_in,
                              void* d_out, int out_size, void* d_ws, size_t ws_size,
                              hipStream_t stream) {
  const float* x = (const float*)d_in[0];     // [2][2048][1024] f32
  const float* W = (const float*)d_in[1];     // [1024][3072] f32
  const int* mask = (const int*)d_in[2];      // [2][2048] i32
  float* out = (float*)d_out;                 // [2][2048][1024] f32
  char* ws = (char*)d_ws;

  ushort* wt = (ushort*)(ws);                                  // 6,291,456 B
  ushort* qw = (ushort*)(ws + 6291456);                        // 8,388,608 B
  ushort* kw = (ushort*)(ws + 6291456 + 8388608);              // 8,388,608 B
  ushort* vw = (ushort*)(ws + 6291456 + 2 * 8388608);          // 8,388,608 B
  ushort* vt = (ushort*)(ws + 6291456 + 3 * (size_t)8388608);  // 8,388,608 B
  float* biasf = (float*)(ws + 6291456 + 4 * (size_t)8388608); // 16,384 B
  // xh (fp16 x, 8,388,608 B) ALIASES vt: live only until k_gemm finishes;
  // k_vt overwrites the region afterwards (same-stream serial order).
  ushort* xhp = vt;

  k_xh<<<dim3(2048), 256, 0, stream>>>(x, xhp, mask, biasf);
  k_wt<<<dim3(48, 16), 256, 0, stream>>>(W, wt);
  k_gemm<<<dim3(24, 32), 256, 0, stream>>>(xhp, wt, qw, kw, vw);
  k_vt<<<dim3(32, 32), 256, 0, stream>>>(vw, vt);
  k_attn<<<dim3(512), 512, 0, stream>>>(qw, kw, vt, biasf, out);
}

// Round 6
// 104.060 us; speedup vs baseline: 1.2515x; 1.1169x over previous
//
#include <hip/hip_runtime.h>

typedef _Float16 half8 __attribute__((ext_vector_type(8)));
typedef float f32x4 __attribute__((ext_vector_type(4)));

#define MFMA16(a, b, c) __builtin_amdgcn_mfma_f32_16x16x32_f16((a), (b), (c), 0, 0, 0)

static __device__ __forceinline__ unsigned short hfbits(float f) {
  return __builtin_bit_cast(unsigned short, (_Float16)f);
}

// async global->LDS, 16B per lane; LDS dest = uniform base + lane*16
static __device__ __forceinline__ void gl16(const ushort* g, ushort* l) {
  __builtin_amdgcn_global_load_lds(
      (const __attribute__((address_space(1))) unsigned int*)g,
      (__attribute__((address_space(3))) unsigned int*)l, 16, 0, 0);
}

// ---------------------------------------------------------------------------
// Kernel 1 (merged prep): blocks [0,768): W f32 -> Wt fp16 transposed;
// blocks [768,2816): x f32 -> xh fp16 (8 elem/thread); block 768 also builds
// biasf {0,-1e9} from mask.
// ---------------------------------------------------------------------------
__global__ __launch_bounds__(256) void k_prep(const float* __restrict__ W,
                                              ushort* __restrict__ wt,
                                              const float* __restrict__ x,
                                              ushort* __restrict__ xh,
                                              const int* __restrict__ mask,
                                              float* __restrict__ biasf) {
  __shared__ ushort tile[64][72];
  const int id = blockIdx.x;
  const int t = threadIdx.x;

  if (id >= 768) {                       // ---- xh cast part
    const int pb = id - 768;
    const size_t p = ((size_t)pb * 256 + t) * 8;
    float4 a = *reinterpret_cast<const float4*>(x + p);
    float4 b = *reinterpret_cast<const float4*>(x + p + 4);
    union { ushort u[8]; uint4 v; } pk;
    pk.u[0] = hfbits(a.x); pk.u[1] = hfbits(a.y);
    pk.u[2] = hfbits(a.z); pk.u[3] = hfbits(a.w);
    pk.u[4] = hfbits(b.x); pk.u[5] = hfbits(b.y);
    pk.u[6] = hfbits(b.z); pk.u[7] = hfbits(b.w);
    *reinterpret_cast<uint4*>(xh + p) = pk.v;
    if (pb == 0) {
#pragma unroll
      for (int i = 0; i < 16; ++i) {
        int q = t + i * 256;
        biasf[q] = mask[q] ? 0.f : -1e9f;
      }
    }
    return;
  }

  // ---- Wt transpose part (id in [0,768): bx = id%48, by = id/48)
  const int n0 = (id % 48) * 64, k0 = (id / 48) * 64;
#pragma unroll
  for (int i = 0; i < 4; ++i) {
    int p = t + i * 256;
    int r = p >> 4, c = (p & 15) << 2;
    float4 v = *reinterpret_cast<const float4*>(&W[(size_t)(k0 + r) * 3072 + n0 + c]);
    ushort4 u;
    u.x = hfbits(v.x); u.y = hfbits(v.y); u.z = hfbits(v.z); u.w = hfbits(v.w);
    *reinterpret_cast<ushort4*>(&tile[r][c]) = u;
  }
  __syncthreads();
#pragma unroll
  for (int i = 0; i < 4; ++i) {
    int p = t + i * 256;
    int rn = p >> 4, ck = (p & 15) << 2;
    ushort4 u;
    u.x = tile[ck + 0][rn]; u.y = tile[ck + 1][rn];
    u.z = tile[ck + 2][rn]; u.w = tile[ck + 3][rn];
    *reinterpret_cast<ushort4*>(&wt[(size_t)(n0 + rn) * 1024 + k0 + ck]) = u;
  }
}

// ---------------------------------------------------------------------------
// Kernel 2: qkv = xh @ W (fp16, gl16-staged, XOR-swizzled LDS, m97 2-barrier
// loop).  NEW vs R5:
//  (a) XCD-chunked decode: 12bn x 8bm chunk per XCD -> L2 working set
//      2MB(A)+3MB(B) instead of 8.4MB A-thrash.
//  (b) V blocks (bn>=16) write vt [bh][d][s] DIRECTLY via per-wave LDS
//      transpose quadrant (slot XOR swizzle, own-wave readback, no extra
//      barrier) -> k_vt kernel deleted (~33MB traffic saved).
// Q outputs pre-scaled by log2(e) (exp2 path in k_attn).
// ---------------------------------------------------------------------------
__global__ __launch_bounds__(256) void k_gemm(const ushort* __restrict__ xh,
                                              const ushort* __restrict__ wt,
                                              ushort* __restrict__ qw,
                                              ushort* __restrict__ kw,
                                              ushort* __restrict__ vt) {
  __shared__ __align__(16) ushort sA[128 * 64];   // 16 KB linear, swizzled
  __shared__ __align__(16) ushort sB[128 * 64];   // 16 KB linear, swizzled
  const int t = threadIdx.x;
  const int lane = t & 63, w = t >> 6;
  const int g = lane >> 4, lr = lane & 15;
  const int wr = w >> 1, wc = w & 1;

  // XCD-chunked decode: chunk (xcd) = 12 bn x 8 bm, bn-fast within chunk.
  const int id = blockIdx.x;
  const int xcd = id & 7, wi = id >> 3;            // wi in 0..95
  const int bn = (xcd & 1) * 12 + wi % 12;
  const int bm = (xcd >> 1) * 8 + wi / 12;

  // staging geometry: wave w stages chunks 4w..4w+3 (1KB each) of A and B.
  int srow[4], soff[4];
#pragma unroll
  for (int i = 0; i < 4; ++i) {
    const int c = 4 * w + i;
    const int r = c * 8 + (lane >> 3);
    const int sl = (lane & 7) ^ (((r & 3) << 1) ^ ((r >> 3) & 3));
    srow[i] = r;
    soff[i] = sl * 8;
  }

  // read-side swizzle per fragment row (depends on lr only)
  int raswz[4], rbswz[4];
#pragma unroll
  for (int rs = 0; rs < 4; ++rs) {
    const int ra = wr * 64 + rs * 16 + lr;
    raswz[rs] = ((((ra & 3) << 1) ^ ((ra >> 3) & 3)) << 4);
    const int rb = wc * 64 + rs * 16 + lr;
    rbswz[rs] = ((((rb & 3) << 1) ^ ((rb >> 3) & 3)) << 4);
  }

  f32x4 acc[4][4] = {};

  for (int kt = 0; kt < 1024; kt += 64) {
#pragma unroll
    for (int i = 0; i < 4; ++i) {
      gl16(xh + (size_t)(bm * 128 + srow[i]) * 1024 + kt + soff[i],
           sA + (4 * w + i) * 512);
      gl16(wt + (size_t)(bn * 128 + srow[i]) * 1024 + kt + soff[i],
           sB + (4 * w + i) * 512);
    }
    __syncthreads();
#pragma unroll
    for (int ks = 0; ks < 64; ks += 32) {
      half8 af[4], bb[4];
#pragma unroll
      for (int rs = 0; rs < 4; ++rs) {
        const int ra = wr * 64 + rs * 16 + lr;
        af[rs] = *reinterpret_cast<const half8*>(
            (const char*)sA + ra * 128 + ((16 * g + 2 * ks) ^ raswz[rs]));
      }
#pragma unroll
      for (int cs = 0; cs < 4; ++cs) {
        const int rb = wc * 64 + cs * 16 + lr;
        bb[cs] = *reinterpret_cast<const half8*>(
            (const char*)sB + rb * 128 + ((16 * g + 2 * ks) ^ rbswz[cs]));
      }
#pragma unroll
      for (int rs = 0; rs < 4; ++rs)
#pragma unroll
        for (int cs = 0; cs < 4; ++cs)
          acc[rs][cs] = MFMA16(af[rs], bb[cs], acc[rs][cs]);
    }
    __syncthreads();
  }

  const int m0 = bm * 128 + wr * 64;
  const int n0 = bn * 128 + wc * 64;
  const int which = n0 >> 10;          // 0=q 1=k 2=v (uniform per wave)
  const int h = (n0 >> 6) & 15;

  if (which == 2) {
    // ---- V: per-wave LDS-quadrant transpose, then coalesced vt store.
    // write: quadrant[n][slot=(m>>3)^(n&7)][m&7] = acc  (n=local d, m=local s)
    ushort* q = (w < 2) ? sA + w * 4096 : sB + (w - 2) * 4096;
#pragma unroll
    for (int rs = 0; rs < 4; ++rs)
#pragma unroll
      for (int r = 0; r < 4; ++r) {
        const int m = rs * 16 + g * 4 + r;
#pragma unroll
        for (int cs = 0; cs < 4; ++cs) {
          const int n = cs * 16 + lr;
          q[n * 64 + ((((m >> 3) ^ (n & 7)) << 3) | (m & 7))] =
              hfbits(acc[rs][cs][r]);
        }
      }
    // own-wave readback (compiler inserts lgkmcnt): 8 rows x 8 lanes per iter
    const int vb = m0 >> 11, vs = m0 & 2047;
    ushort* vbase = vt + ((size_t)((vb << 4) + h) * 64) * 2048 + vs;
#pragma unroll
    for (int j = 0; j < 8; ++j) {
      const int dl = j * 8 + (lane >> 3);
      const int mc = lane & 7;
      uint4 vv = *reinterpret_cast<const uint4*>(
          q + dl * 64 + ((mc ^ (dl & 7)) << 3));
      *reinterpret_cast<uint4*>(vbase + (size_t)dl * 2048 + mc * 8) = vv;
    }
  } else {
    ushort* dst = which == 0 ? qw : kw;
    const float qsc = which == 0 ? 1.44269504088896f : 1.0f;  // log2(e) for Q
#pragma unroll
    for (int rs = 0; rs < 4; ++rs) {
#pragma unroll
      for (int r = 0; r < 4; ++r) {
        int m = m0 + rs * 16 + g * 4 + r;
        int b = m >> 11, s = m & 2047;
        ushort* rowp = dst + ((size_t)((b << 4) + h) * 2048 + s) * 64;
#pragma unroll
        for (int cs = 0; cs < 4; ++cs)
          rowp[cs * 16 + lr] = hfbits(acc[rs][cs][r] * qsc);
      }
    }
  }
}

// ---------------------------------------------------------------------------
// Kernel 3: flash attention (unchanged from R4/R5: 8 waves, bias-in-C,
// ones-column denominator MFMA, exp2, defer-max, XCD-clustered decode).
// ---------------------------------------------------------------------------
__global__ __launch_bounds__(512) void k_attn(const ushort* __restrict__ qw,
                                              const ushort* __restrict__ kw,
                                              const ushort* __restrict__ vt,
                                              const float* __restrict__ biasf,
                                              float* __restrict__ out) {
  __shared__ __align__(16) ushort sK[2][64][64];   // 16 KB (2 bufs)
  __shared__ __align__(16) ushort sV[2][64][64];   // 16 KB (2 bufs)

  const int t = threadIdx.x;
  const int lane = t & 63, w = t >> 6;             // w in 0..7
  const int g = lane >> 4, lr = lane & 15;

  // XCD-clustered decode: id%8 = XCD; 4 bh x 16 qblk per XCD.
  const int id = blockIdx.x;                        // 0..511
  const int j = id >> 3;
  const int bh = (id & 7) * 4 + (j >> 4);
  const int qblk = j & 15;
  const int b = bh >> 4, h = bh & 15;

  const int qrow = qblk * 128 + w * 16 + lr;
  const ushort* qp = qw + ((size_t)bh * 2048 + qrow) * 64;
  const half8 qb0 = *reinterpret_cast<const half8*>(qp + g * 8);
  const half8 qb1 = *reinterpret_cast<const half8*>(qp + 32 + g * 8);

  const ushort* kbh = kw + (size_t)bh * 2048 * 64;
  const ushort* vbh = vt + (size_t)bh * 64 * 2048;
  const float* biasb = biasf + b * 2048;

  const int krbase = (lr >> 2) * 8 + (lr & 3);
  const int kswz = (((lr & 3) << 1) ^ (lr >> 2)) << 4;

  const int sr0 = w * 8 + (lane >> 3);
  const int scb = (lane & 7) << 4;
  const int swz0 = scb ^ ((((sr0 & 3) << 1) ^ ((sr0 >> 3) & 3)) << 4);

  auto stage = [&](int bufi, int jtn) {
    gl16(kbh + (size_t)(jtn + sr0) * 64 + (swz0 >> 1), &sK[bufi][0][0] + w * 512);
    gl16(vbh + (size_t)sr0 * 2048 + jtn + (swz0 >> 1), &sV[bufi][0][0] + w * 512);
  };

  const half8 vones = {(_Float16)1.f, (_Float16)1.f, (_Float16)1.f, (_Float16)1.f,
                       (_Float16)1.f, (_Float16)1.f, (_Float16)1.f, (_Float16)1.f};

  float m_run = -__builtin_inff();
  f32x4 o[4] = {};
  f32x4 oden = {};

  stage(0, 0);
  __syncthreads();
  int buf = 0;

  for (int jt = 0; jt < 2048; jt += 64) {
    if (jt + 64 < 2048) stage(buf ^ 1, jt + 64);

    f32x4 bias4[4];
#pragma unroll
    for (int jn = 0; jn < 4; ++jn) {
      const int koff = (jn & 1) * 4 + (jn >> 1) * 32;
      bias4[jn] = *reinterpret_cast<const f32x4*>(biasb + jt + koff + g * 8);
    }

    half8 vf0[4], vf1[4];
#pragma unroll
    for (int dn = 0; dn < 4; ++dn) {
      const int vr = dn * 16 + lr;
      const int vswz = ((((lr & 3) << 1) ^ ((2 * dn + (lr >> 3)) & 3)) << 4);
      const char* vrow = (const char*)&sV[buf][vr][0];
      vf0[dn] = *reinterpret_cast<const half8*>(vrow + ((16 * g) ^ vswz));
      vf1[dn] = *reinterpret_cast<const half8*>(vrow + ((64 + 16 * g) ^ vswz));
    }

    float st[4][4];
#pragma unroll
    for (int jn = 0; jn < 4; ++jn) {
      const int koff = (jn & 1) * 4 + (jn >> 1) * 32;
      const int kr = koff + krbase;
      const char* krow = (const char*)&sK[buf][kr][0];
      half8 ka0 = *reinterpret_cast<const half8*>(krow + ((16 * g) ^ kswz));
      half8 ka1 = *reinterpret_cast<const half8*>(krow + ((64 + 16 * g) ^ kswz));
      f32x4 s4 = bias4[jn];
      s4 = MFMA16(ka0, qb0, s4);
      s4 = MFMA16(ka1, qb1, s4);
#pragma unroll
      for (int r = 0; r < 4; ++r) st[jn][r] = s4[r];
    }

    float ma = fmaxf(fmaxf(st[0][0], st[0][1]), st[0][2]);
    ma = fmaxf(fmaxf(ma, st[0][3]), st[1][0]);
    ma = fmaxf(fmaxf(ma, st[1][1]), st[1][2]);
    ma = fmaxf(ma, st[1][3]);
    float mb2 = fmaxf(fmaxf(st[2][0], st[2][1]), st[2][2]);
    mb2 = fmaxf(fmaxf(mb2, st[2][3]), st[3][0]);
    mb2 = fmaxf(fmaxf(mb2, st[3][1]), st[3][2]);
    mb2 = fmaxf(mb2, st[3][3]);
    float tmax = fmaxf(ma, mb2);
    tmax = fmaxf(tmax, __shfl_xor(tmax, 16));
    tmax = fmaxf(tmax, __shfl_xor(tmax, 32));

    if (!__all(tmax <= m_run + 8.f)) {
      const float mnew = fmaxf(m_run, tmax);
      const float sc = __builtin_amdgcn_exp2f(m_run - mnew);  // exp2(-inf)=0
      const float s0 = __shfl(sc, g * 4 + 0);
      const float s1 = __shfl(sc, g * 4 + 1);
      const float s2 = __shfl(sc, g * 4 + 2);
      const float s3 = __shfl(sc, g * 4 + 3);
#pragma unroll
      for (int dn = 0; dn < 4; ++dn) {
        o[dn][0] *= s0; o[dn][1] *= s1; o[dn][2] *= s2; o[dn][3] *= s3;
      }
      oden[0] *= s0; oden[1] *= s1; oden[2] *= s2; oden[3] *= s3;
      m_run = mnew;
    }

    unsigned int pd[8];
#pragma unroll
    for (int jn = 0; jn < 4; ++jn) {
      float p0 = __builtin_amdgcn_exp2f(st[jn][0] - m_run);
      float p1 = __builtin_amdgcn_exp2f(st[jn][1] - m_run);
      float p2 = __builtin_amdgcn_exp2f(st[jn][2] - m_run);
      float p3 = __builtin_amdgcn_exp2f(st[jn][3] - m_run);
      pd[jn * 2 + 0] = __builtin_bit_cast(unsigned int, __builtin_amdgcn_cvt_pkrtz(p0, p1));
      pd[jn * 2 + 1] = __builtin_bit_cast(unsigned int, __builtin_amdgcn_cvt_pkrtz(p2, p3));
    }

    union { unsigned int u[4]; half8 h; } pa0u, pa1u;
    pa0u.u[0] = pd[0]; pa0u.u[1] = pd[1]; pa0u.u[2] = pd[2]; pa0u.u[3] = pd[3];
    pa1u.u[0] = pd[4]; pa1u.u[1] = pd[5]; pa1u.u[2] = pd[6]; pa1u.u[3] = pd[7];

    __builtin_amdgcn_s_setprio(1);
#pragma unroll
    for (int dn = 0; dn < 4; ++dn) {
      o[dn] = MFMA16(pa0u.h, vf0[dn], o[dn]);
      o[dn] = MFMA16(pa1u.h, vf1[dn], o[dn]);
    }
    oden = MFMA16(pa0u.h, vones, oden);
    oden = MFMA16(pa1u.h, vones, oden);
    __builtin_amdgcn_s_setprio(0);

    __syncthreads();
    buf ^= 1;
  }

  const float i0 = 1.f / oden[0];
  const float i1 = 1.f / oden[1];
  const float i2 = 1.f / oden[2];
  const float i3 = 1.f / oden[3];
  const int s0r = qblk * 128 + w * 16 + g * 4;
  float* ob = out + ((size_t)b * 2048 + s0r) * 1024 + h * 64;
#pragma unroll
  for (int dn = 0; dn < 4; ++dn) {
    ob[0 * 1024 + dn * 16 + lr] = o[dn][0] * i0;
    ob[1 * 1024 + dn * 16 + lr] = o[dn][1] * i1;
    ob[2 * 1024 + dn * 16 + lr] = o[dn][2] * i2;
    ob[3 * 1024 + dn * 16 + lr] = o[dn][3] * i3;
  }
}

// ---------------------------------------------------------------------------
extern "C" void kernel_launch(void* const* d_in, const int* in_sizes, int n_in,
                              void* d_out, int out_size, void* d_ws, size_t ws_size,
                              hipStream_t stream) {
  const float* x = (const float*)d_in[0];     // [2][2048][1024] f32
  const float* W = (const float*)d_in[1];     // [1024][3072] f32
  const int* mask = (const int*)d_in[2];      // [2][2048] i32
  float* out = (float*)d_out;                 // [2][2048][1024] f32
  char* ws = (char*)d_ws;

  ushort* wt = (ushort*)(ws);                                  // 6,291,456 B
  ushort* qw = (ushort*)(ws + 6291456);                        // 8,388,608 B
  ushort* kw = (ushort*)(ws + 6291456 + 8388608);              // 8,388,608 B
  ushort* xh = (ushort*)(ws + 6291456 + 2 * (size_t)8388608);  // 8,388,608 B (old vw slot)
  ushort* vt = (ushort*)(ws + 6291456 + 3 * (size_t)8388608);  // 8,388,608 B
  float* biasf = (float*)(ws + 6291456 + 4 * (size_t)8388608); // 16,384 B

  k_prep<<<dim3(2816), 256, 0, stream>>>(W, wt, x, xh, mask, biasf);
  k_gemm<<<dim3(768), 256, 0, stream>>>(xh, wt, qw, kw, vt);
  k_attn<<<dim3(512), 512, 0, stream>>>(qw, kw, vt, biasf, out);
}